// Round 4
// baseline (269.622 us; speedup 1.0000x reference)
//
#include <hip/hip_runtime.h>

#define NB 4
#define SEQ 4096
#define DIM 1024
#define DFF 4096
#define KSEL 2048
#define NTOK (NB * SEQ)   // 16384
#define MR (NB * KSEL)    // 8192

typedef float f32x4_t __attribute__((ext_vector_type(4)));
typedef __bf16 bf16x8_t __attribute__((ext_vector_type(8)));

__device__ __forceinline__ unsigned short f2bf(float f) {
  union { float f; unsigned u; } v; v.f = f;
  unsigned r = v.u + 0x7fffu + ((v.u >> 16) & 1u);  // RNE
  return (unsigned short)(r >> 16);
}

#define GLD16(g, l) __builtin_amdgcn_global_load_lds( \
    (const __attribute__((address_space(1))) void*)(g), \
    (__attribute__((address_space(3))) void*)(l), 16, 0, 0)

// ---- fused router GEMV + full x->out copy (one wave per row) ----
__global__ void router_copy_kernel(const float* __restrict__ x, const float* __restrict__ Wr,
                                   const float* __restrict__ br, float* __restrict__ out,
                                   float* __restrict__ logits, float* __restrict__ scores) {
  int lane = threadIdx.x & 63;
  int wid  = threadIdx.x >> 6;
  int row  = blockIdx.x * 4 + wid;            // 0..16383
  const float4* xr = (const float4*)(x + (size_t)row * DIM);
  float4* orow = (float4*)(out + (size_t)row * DIM);
  const float4* w4 = (const float4*)Wr;
  float sum = 0.f;
#pragma unroll
  for (int i = 0; i < 4; ++i) {
    float4 a = xr[lane + i * 64];
    float4 w = w4[lane + i * 64];
    orow[lane + i * 64] = a;
    sum += a.x * w.x + a.y * w.y + a.z * w.z + a.w * w.w;
  }
#pragma unroll
  for (int off = 32; off > 0; off >>= 1) sum += __shfl_down(sum, off);
  if (lane == 0) {
    float l = sum + br[0];
    logits[row] = l;
    scores[row] = 1.f / (1.f + expf(-l));
  }
}

// ---- exact top-k via rank counting (matches jax.lax.top_k tie-break) ----
// 16 tokens/block; each token's scan split across 16 lanes of one wave.
__global__ void rank_kernel(const float* __restrict__ scores, int* __restrict__ sel) {
  __shared__ float s_sc[SEQ];
  int batch = blockIdx.x >> 8;        // 256 blocks per batch
  int chunk = blockIdx.x & 255;
  int t = threadIdx.x;                // 256
  const float4* sb4 = (const float4*)(scores + batch * SEQ);
  float4* ls4 = (float4*)s_sc;
#pragma unroll
  for (int i = 0; i < 4; ++i) ls4[t + i * 256] = sb4[t + i * 256];
  __syncthreads();
  int tok = chunk * 16 + (t >> 4);    // token this thread contributes to
  int sg  = t & 15;                   // score segment 0..15 (256 scores each)
  float s = s_sc[tok];
  const float4* seg = ls4 + sg * 64;
  int jbase = sg * 256;
  int rank = 0;
#pragma unroll 4
  for (int j4 = 0; j4 < 64; ++j4) {
    float4 v = seg[j4];
    int j = jbase + j4 * 4;
    rank += (v.x > s || (v.x == s && j     < tok)) ? 1 : 0;
    rank += (v.y > s || (v.y == s && j + 1 < tok)) ? 1 : 0;
    rank += (v.z > s || (v.z == s && j + 2 < tok)) ? 1 : 0;
    rank += (v.w > s || (v.w == s && j + 3 < tok)) ? 1 : 0;
  }
#pragma unroll
  for (int off = 8; off > 0; off >>= 1) rank += __shfl_down(rank, off, 16);
  if (sg == 0) sel[batch * SEQ + tok] = (rank < KSEL) ? 1 : 0;
}

// ---- per-batch: softmax over selected scores + prefix-sum compaction ----
__global__ void pack_kernel(const float* __restrict__ scores, const int* __restrict__ sel,
                            int* __restrict__ rows, float* __restrict__ rwv) {
  __shared__ float red[16];
  __shared__ int scn[1024];
  int batch = blockIdx.x;
  int t = threadIdx.x;
  const float* sb = scores + batch * SEQ;
  const int* fb = sel + batch * SEQ;
  float sc[4]; int fl[4];
#pragma unroll
  for (int i = 0; i < 4; ++i) { sc[i] = sb[t * 4 + i]; fl[i] = fb[t * 4 + i]; }
  float m = fmaxf(fmaxf(sc[0], sc[1]), fmaxf(sc[2], sc[3]));
#pragma unroll
  for (int off = 32; off > 0; off >>= 1) m = fmaxf(m, __shfl_down(m, off));
  if ((t & 63) == 0) red[t >> 6] = m;
  __syncthreads();
  if (t == 0) { float v = red[0]; for (int i = 1; i < 16; ++i) v = fmaxf(v, red[i]); red[0] = v; }
  __syncthreads();
  m = red[0];
  __syncthreads();
  float ex[4]; float esum = 0.f;
#pragma unroll
  for (int i = 0; i < 4; ++i) { ex[i] = expf(sc[i] - m); if (fl[i]) esum += ex[i]; }
#pragma unroll
  for (int off = 32; off > 0; off >>= 1) esum += __shfl_down(esum, off);
  if ((t & 63) == 0) red[t >> 6] = esum;
  __syncthreads();
  if (t == 0) { float v = 0.f; for (int i = 0; i < 16; ++i) v += red[i]; red[0] = v; }
  __syncthreads();
  float total = red[0];
  int cnt = fl[0] + fl[1] + fl[2] + fl[3];
  scn[t] = cnt;
  __syncthreads();
  for (int off = 1; off < 1024; off <<= 1) {
    int a = scn[t];
    int b = (t >= off) ? scn[t - off] : 0;
    __syncthreads();
    scn[t] = a + b;
    __syncthreads();
  }
  int p = scn[t] - cnt;
#pragma unroll
  for (int i = 0; i < 4; ++i) {
    if (fl[i]) {
      rows[batch * KSEL + p] = t * 4 + i;
      rwv[batch * KSEL + p]  = ex[i] / total;
      ++p;
    }
  }
}

// ---- gather selected rows of x -> bf16 compact matrix ----
__global__ void gather_kernel(const float* __restrict__ x, const int* __restrict__ rows,
                              unsigned short* __restrict__ Xc) {
  int mrow = blockIdx.x;           // 0..8191
  int batch = mrow >> 11;
  int tok = rows[mrow];
  const float4* src = (const float4*)(x + ((size_t)(batch * SEQ + tok)) * DIM);
  ushort4* dst = (ushort4*)(Xc + (size_t)mrow * DIM);
  int t = threadIdx.x;             // 256
  float4 v = src[t];
  ushort4 o;
  o.x = f2bf(v.x); o.y = f2bf(v.y); o.z = f2bf(v.z); o.w = f2bf(v.w);
  dst[t] = o;
}

// ---- transpose + cast f32 [R][C] -> bf16 [C][R] ----
__global__ void transpose_cast(const float* __restrict__ W, unsigned short* __restrict__ Wt,
                               int R, int C) {
  __shared__ float tl[32][33];
  int c0 = blockIdx.x * 32;
  int r0 = blockIdx.y * 32;
  int tx = threadIdx.x, ty = threadIdx.y;
#pragma unroll
  for (int i = 0; i < 4; ++i)
    tl[ty + i * 8][tx] = W[(size_t)(r0 + ty + i * 8) * C + c0 + tx];
  __syncthreads();
#pragma unroll
  for (int i = 0; i < 4; ++i)
    Wt[(size_t)(c0 + ty + i * 8) * R + r0 + tx] = f2bf(tl[tx][ty + i * 8]);
}

// ==== 256x128 triple-buffered counted-vmcnt bf16 MFMA GEMM, B^T layout ====
// BM=256, BN=128, BK=64, 512 threads = 8 waves (2M x 4N), per-wave 128x32.
// 3 LDS buffers (48 KB each): tile t reads buf t%3; stage(t+2) issued at
// tile t into buf (t+2)%3 -> 2-tile issue-to-complete slack; drain with
// s_waitcnt vmcnt(6) (oldest tile only), never 0 except peeled last tile.
// One barrier per K-tile. LDS XOR-swizzle byte^=((row&7)<<4) via
// pre-swizzled global source + swizzled ds_read.
// EPI=1: H = bf16(gelu(acc+b1));  EPI=2: out[scatter] = x + rw*(acc+b2)
template <int EPI>
__global__ __launch_bounds__(512, 2)
void gemm3(const unsigned short* __restrict__ A, const unsigned short* __restrict__ Bt,
           int M, int N, int K,
           const float* __restrict__ bias,
           unsigned short* __restrict__ Hout,
           const float* __restrict__ x,
           const int* __restrict__ rows,
           const float* __restrict__ rwv,
           float* __restrict__ out) {
  constexpr int BN = 128;
  constexpr int ABYTES = 256 * 128;        // 32 KB per buffer
  constexpr int BBYTES = BN * 128;         // 16 KB
  constexpr int TBYTES = ABYTES + BBYTES;  // 48 KB
  __shared__ __align__(16) char lds[3 * TBYTES];   // 144 KB

  const int t = threadIdx.x;
  const int lane = t & 63;
  const int wid = t >> 6;
  const int wm = wid >> 2;                 // 0..1
  const int wn = wid & 3;                  // 0..3

  // XCD-aware bijective swizzle (gridDim.x % 8 == 0 by construction)
  const int nwg = gridDim.x;
  const int qq = nwg >> 3;
  const int nid = (blockIdx.x & 7) * qq + (blockIdx.x >> 3);
  const int gx = N / BN;
  const int by = nid / gx;
  const int bx = nid - by * gx;
  const int bm0 = by * 256;
  const int bn0 = bx * BN;

  const size_t ldb = (size_t)K * 2;        // row bytes for A and Bt
  const char* Ab = (const char*)A;
  const char* Bb = (const char*)Bt;

  // staging: thread t covers LDS bytes [t*16, t*16+16) of each 64-row chunk;
  // chunk row = t>>3, dest slot = t&7, source slot = (t&7)^(row&7)
  const int srow = t >> 3;
  const size_t stage_off = (size_t)srow * ldb + (size_t)((((t & 7) ^ (srow & 7)) * 16));

  // ds_read fragment offsets (swizzled): row = ...+(lane&15), slot=(lane>>4)
  const int arow0 = wm * 128 + (lane & 15);
  const int brow0 = wn * 32 + (lane & 15);
  const int cbs0 = (((lane >> 4) * 16)     ) ^ ((lane & 7) << 4);  // kk=0
  const int cbs1 = (64 + (lane >> 4) * 16) ^ ((lane & 7) << 4);    // kk=1

  f32x4_t acc[8][2];
  f32x4_t zero = {0.f, 0.f, 0.f, 0.f};
#pragma unroll
  for (int i = 0; i < 8; ++i) { acc[i][0] = zero; acc[i][1] = zero; }

  const int NT = K / 64;

  auto stage = [&](int buf, int kt) {
    char* base = lds + buf * TBYTES;
    const char* abase = Ab + (size_t)bm0 * ldb + (size_t)kt * 128 + stage_off;
#pragma unroll
    for (int c = 0; c < 4; ++c)
      GLD16(abase + (size_t)(c * 64) * ldb, base + t * 16 + c * 8192);
    const char* bbase = Bb + (size_t)bn0 * ldb + (size_t)kt * 128 + stage_off;
#pragma unroll
    for (int c = 0; c < 2; ++c)
      GLD16(bbase + (size_t)(c * 64) * ldb, base + ABYTES + t * 16 + c * 8192);
  };

  auto compute = [&](int buf) {
    const char* Al = lds + buf * TBYTES;
    const char* Bl = Al + ABYTES;
    bf16x8_t bq[2][2];
#pragma unroll
    for (int n = 0; n < 2; ++n) {
      const char* bp = Bl + (brow0 + n * 16) * 128;
      bq[n][0] = *(const bf16x8_t*)(bp + cbs0);
      bq[n][1] = *(const bf16x8_t*)(bp + cbs1);
    }
#pragma unroll
    for (int half = 0; half < 2; ++half) {
      bf16x8_t am[4][2];
#pragma unroll
      for (int mi = 0; mi < 4; ++mi) {
        const char* ap = Al + (arow0 + (half * 4 + mi) * 16) * 128;
        am[mi][0] = *(const bf16x8_t*)(ap + cbs0);
        am[mi][1] = *(const bf16x8_t*)(ap + cbs1);
      }
      __builtin_amdgcn_s_setprio(1);
#pragma unroll
      for (int mi = 0; mi < 4; ++mi)
#pragma unroll
        for (int n = 0; n < 2; ++n) {
          acc[half * 4 + mi][n] = __builtin_amdgcn_mfma_f32_16x16x32_bf16(
              am[mi][0], bq[n][0], acc[half * 4 + mi][n], 0, 0, 0);
          acc[half * 4 + mi][n] = __builtin_amdgcn_mfma_f32_16x16x32_bf16(
              am[mi][1], bq[n][1], acc[half * 4 + mi][n], 0, 0, 0);
        }
      __builtin_amdgcn_s_setprio(0);
    }
  };

  // prologue: stage tiles 0,1 (12 loads in flight)
  stage(0, 0);
  stage(1, 1);

  for (int kt = 0; kt < NT - 1; ++kt) {
    // oldest tile's 6 loads complete; next tile's 6 may stay in flight
    asm volatile("s_waitcnt vmcnt(6)" ::: "memory");
    __builtin_amdgcn_s_barrier();
    __builtin_amdgcn_sched_barrier(0);
    if (kt + 2 < NT) stage((kt + 2) % 3, kt + 2);
    compute(kt % 3);
  }
  // peeled last tile: full drain (only its own 6 loads remain)
  asm volatile("s_waitcnt vmcnt(0)" ::: "memory");
  __builtin_amdgcn_s_barrier();
  __builtin_amdgcn_sched_barrier(0);
  compute((NT - 1) % 3);

  // epilogue  (C/D: row = (lane>>4)*4 + qi (M), col = lane&15 (N))
  const int rb = (lane >> 4) * 4;
  const int cc = lane & 15;
  float bs[2];
#pragma unroll
  for (int n = 0; n < 2; ++n)
    bs[n] = bias[bn0 + wn * 32 + n * 16 + cc];
#pragma unroll
  for (int m = 0; m < 8; ++m) {
#pragma unroll
    for (int qi = 0; qi < 4; ++qi) {
      int grow = bm0 + wm * 128 + m * 16 + rb + qi;
      if (EPI == 1) {
#pragma unroll
        for (int n = 0; n < 2; ++n) {
          int gcol = bn0 + wn * 32 + n * 16 + cc;
          float v = acc[m][n][qi] + bs[n];
          float cp = 0.7978845608028654f * (v + 0.044715f * v * v * v);
          float g = v / (1.f + __expf(-2.f * cp));   // tanh-approx gelu
          Hout[(size_t)grow * N + gcol] = f2bf(g);
        }
      } else {
        int batch = grow >> 11;
        int tok = rows[grow];
        float rw = rwv[grow];
        size_t obase = ((size_t)(batch * SEQ + tok)) * DIM;
#pragma unroll
        for (int n = 0; n < 2; ++n) {
          int gcol = bn0 + wn * 32 + n * 16 + cc;
          float v = acc[m][n][qi] + bs[n];
          out[obase + gcol] = x[obase + gcol] + rw * v;
        }
      }
    }
  }
}

// ---- aux BCE loss reduction ----
__global__ void aux_kernel(const float* __restrict__ logits, const int* __restrict__ sel,
                           float* __restrict__ out, int out_size) {
  __shared__ float red[16];
  int t = threadIdx.x;
  float sum = 0.f;
  for (int i = t; i < NTOK; i += 1024) {
    float l = logits[i];
    float tgt = sel[i] ? 1.f : 0.f;
    sum += fmaxf(l, 0.f) - l * tgt + log1pf(expf(-fabsf(l)));
  }
#pragma unroll
  for (int off = 32; off > 0; off >>= 1) sum += __shfl_down(sum, off);
  if ((t & 63) == 0) red[t >> 6] = sum;
  __syncthreads();
  if (t == 0) {
    float v = 0.f;
    for (int i = 0; i < 16; ++i) v += red[i];
    out[out_size - 1] = v / (float)NTOK;
  }
}

extern "C" void kernel_launch(void* const* d_in, const int* in_sizes, int n_in,
                              void* d_out, int out_size, void* d_ws, size_t ws_size,
                              hipStream_t stream) {
  const float* x  = (const float*)d_in[0];
  // d_in[1] = attention_mask (unused by reference)
  const float* Wr = (const float*)d_in[2];
  const float* br = (const float*)d_in[3];
  const float* W1 = (const float*)d_in[4];
  const float* b1 = (const float*)d_in[5];
  const float* W2 = (const float*)d_in[6];
  const float* b2 = (const float*)d_in[7];
  float* out = (float*)d_out;

  char* ws = (char*)d_ws;
  float* logits = (float*)(ws);
  float* scores = (float*)(ws + 65536);
  int*   sel    = (int*)(ws + 131072);
  int*   rows   = (int*)(ws + 196608);
  float* rwv    = (float*)(ws + 229376);
  unsigned short* W1t = (unsigned short*)(ws + 262144);
  unsigned short* W2t = (unsigned short*)(ws + 262144 + 8388608);
  unsigned short* Xc  = (unsigned short*)(ws + 262144 + 2 * 8388608);
  unsigned short* H   = (unsigned short*)(ws + 262144 + 2 * 8388608 + 16777216);

  transpose_cast<<<dim3(DFF / 32, DIM / 32), dim3(32, 8), 0, stream>>>(W1, W1t, DIM, DFF);
  transpose_cast<<<dim3(DIM / 32, DFF / 32), dim3(32, 8), 0, stream>>>(W2, W2t, DFF, DIM);
  router_copy_kernel<<<NTOK / 4, 256, 0, stream>>>(x, Wr, br, out, logits, scores);
  rank_kernel<<<NTOK / 16, 256, 0, stream>>>(scores, sel);
  pack_kernel<<<NB, 1024, 0, stream>>>(scores, sel, rows, rwv);
  gather_kernel<<<MR, 256, 0, stream>>>(x, rows, Xc);
  gemm3<1><<<(MR / 256) * (DFF / 128), 512, 0, stream>>>(
      Xc, W1t, MR, DFF, DIM, b1, H, nullptr, nullptr, nullptr, nullptr);
  gemm3<2><<<(MR / 256) * (DIM / 128), 512, 0, stream>>>(
      H, W2t, MR, DIM, DFF, b2, nullptr, x, rows, rwv, out);
  aux_kernel<<<1, 1024, 0, stream>>>(logits, sel, out, out_size);
}

// Round 5
// 260.931 us; speedup vs baseline: 1.0333x; 1.0333x over previous
//
#include <hip/hip_runtime.h>

#define NB 4
#define SEQ 4096
#define DIM 1024
#define DFF 4096
#define KSEL 2048
#define NTOK (NB * SEQ)   // 16384
#define MR (NB * KSEL)    // 8192

typedef float f32x4_t __attribute__((ext_vector_type(4)));
typedef __bf16 bf16x8_t __attribute__((ext_vector_type(8)));

__device__ __forceinline__ unsigned short f2bf(float f) {
  union { float f; unsigned u; } v; v.f = f;
  unsigned r = v.u + 0x7fffu + ((v.u >> 16) & 1u);  // RNE
  return (unsigned short)(r >> 16);
}

#define GLD16(g, l) __builtin_amdgcn_global_load_lds( \
    (const __attribute__((address_space(1))) void*)(g), \
    (__attribute__((address_space(3))) void*)(l), 16, 0, 0)

// ---- router GEMV (one wave per row) ----
__global__ void router_kernel(const float* __restrict__ x, const float* __restrict__ Wr,
                              const float* __restrict__ br,
                              float* __restrict__ logits, float* __restrict__ scores) {
  int lane = threadIdx.x & 63;
  int wid  = threadIdx.x >> 6;
  int row  = blockIdx.x * 4 + wid;            // 0..16383
  const float4* xr = (const float4*)(x + (size_t)row * DIM);
  const float4* w4 = (const float4*)Wr;
  float sum = 0.f;
#pragma unroll
  for (int i = 0; i < 4; ++i) {
    float4 a = xr[lane + i * 64];
    float4 w = w4[lane + i * 64];
    sum += a.x * w.x + a.y * w.y + a.z * w.z + a.w * w.w;
  }
#pragma unroll
  for (int off = 32; off > 0; off >>= 1) sum += __shfl_down(sum, off);
  if (lane == 0) {
    float l = sum + br[0];
    logits[row] = l;
    scores[row] = 1.f / (1.f + expf(-l));
  }
}

// ---- exact top-k via rank counting (matches jax.lax.top_k tie-break) ----
__global__ void rank_kernel(const float* __restrict__ scores, int* __restrict__ sel) {
  __shared__ float s_sc[SEQ];
  int batch = blockIdx.x >> 8;        // 256 blocks per batch
  int chunk = blockIdx.x & 255;
  int t = threadIdx.x;                // 256
  const float4* sb4 = (const float4*)(scores + batch * SEQ);
  float4* ls4 = (float4*)s_sc;
#pragma unroll
  for (int i = 0; i < 4; ++i) ls4[t + i * 256] = sb4[t + i * 256];
  __syncthreads();
  int tok = chunk * 16 + (t >> 4);    // token this thread contributes to
  int sg  = t & 15;                   // score segment 0..15 (256 scores each)
  float s = s_sc[tok];
  const float4* seg = ls4 + sg * 64;
  int jbase = sg * 256;
  int rank = 0;
#pragma unroll 4
  for (int j4 = 0; j4 < 64; ++j4) {
    float4 v = seg[j4];
    int j = jbase + j4 * 4;
    rank += (v.x > s || (v.x == s && j     < tok)) ? 1 : 0;
    rank += (v.y > s || (v.y == s && j + 1 < tok)) ? 1 : 0;
    rank += (v.z > s || (v.z == s && j + 2 < tok)) ? 1 : 0;
    rank += (v.w > s || (v.w == s && j + 3 < tok)) ? 1 : 0;
  }
#pragma unroll
  for (int off = 8; off > 0; off >>= 1) rank += __shfl_down(rank, off, 16);
  if (sg == 0) sel[batch * SEQ + tok] = (rank < KSEL) ? 1 : 0;
}

// ---- per-batch: softmax over selected scores + prefix-sum compaction ----
__global__ void pack_kernel(const float* __restrict__ scores, const int* __restrict__ sel,
                            int* __restrict__ rows, float* __restrict__ rwv,
                            int* __restrict__ slot) {
  __shared__ float red[16];
  __shared__ int scn[1024];
  int batch = blockIdx.x;
  int t = threadIdx.x;
  const float* sb = scores + batch * SEQ;
  const int* fb = sel + batch * SEQ;
  float sc[4]; int fl[4];
#pragma unroll
  for (int i = 0; i < 4; ++i) { sc[i] = sb[t * 4 + i]; fl[i] = fb[t * 4 + i]; }
  float m = fmaxf(fmaxf(sc[0], sc[1]), fmaxf(sc[2], sc[3]));
#pragma unroll
  for (int off = 32; off > 0; off >>= 1) m = fmaxf(m, __shfl_down(m, off));
  if ((t & 63) == 0) red[t >> 6] = m;
  __syncthreads();
  if (t == 0) { float v = red[0]; for (int i = 1; i < 16; ++i) v = fmaxf(v, red[i]); red[0] = v; }
  __syncthreads();
  m = red[0];
  __syncthreads();
  float ex[4]; float esum = 0.f;
#pragma unroll
  for (int i = 0; i < 4; ++i) { ex[i] = expf(sc[i] - m); if (fl[i]) esum += ex[i]; }
#pragma unroll
  for (int off = 32; off > 0; off >>= 1) esum += __shfl_down(esum, off);
  if ((t & 63) == 0) red[t >> 6] = esum;
  __syncthreads();
  if (t == 0) { float v = 0.f; for (int i = 0; i < 16; ++i) v += red[i]; red[0] = v; }
  __syncthreads();
  float total = red[0];
  int cnt = fl[0] + fl[1] + fl[2] + fl[3];
  scn[t] = cnt;
  __syncthreads();
  for (int off = 1; off < 1024; off <<= 1) {
    int a = scn[t];
    int b = (t >= off) ? scn[t - off] : 0;
    __syncthreads();
    scn[t] = a + b;
    __syncthreads();
  }
  int p = scn[t] - cnt;
#pragma unroll
  for (int i = 0; i < 4; ++i) {
    if (fl[i]) {
      rows[batch * KSEL + p] = t * 4 + i;
      rwv[batch * KSEL + p]  = ex[i] / total;
      slot[batch * SEQ + t * 4 + i] = batch * KSEL + p;
      ++p;
    }
  }
}

// ---- fused: selected rows -> bf16 Xc; unselected rows -> out (= x) ----
__global__ void gather_copy_kernel(const float* __restrict__ x, const int* __restrict__ sel,
                                   const int* __restrict__ slot,
                                   unsigned short* __restrict__ Xc, float* __restrict__ out) {
  int tokg = blockIdx.x;           // 0..16383
  const float4* src = (const float4*)(x + (size_t)tokg * DIM);
  int t = threadIdx.x;             // 256
  float4 v = src[t];
  if (sel[tokg]) {
    ushort4 o;
    o.x = f2bf(v.x); o.y = f2bf(v.y); o.z = f2bf(v.z); o.w = f2bf(v.w);
    ((ushort4*)(Xc + (size_t)slot[tokg] * DIM))[t] = o;
  } else {
    ((float4*)(out + (size_t)tokg * DIM))[t] = v;
  }
}

// ---- transpose + cast f32 [R][C] -> bf16 [C][R] ----
__global__ void transpose_cast(const float* __restrict__ W, unsigned short* __restrict__ Wt,
                               int R, int C) {
  __shared__ float tl[32][33];
  int c0 = blockIdx.x * 32;
  int r0 = blockIdx.y * 32;
  int tx = threadIdx.x, ty = threadIdx.y;
#pragma unroll
  for (int i = 0; i < 4; ++i)
    tl[ty + i * 8][tx] = W[(size_t)(r0 + ty + i * 8) * C + c0 + tx];
  __syncthreads();
#pragma unroll
  for (int i = 0; i < 4; ++i)
    Wt[(size_t)(c0 + ty + i * 8) * R + r0 + tx] = f2bf(tl[tx][ty + i * 8]);
}

// ==== 256xBN 4-phase bf16 MFMA GEMM, counted-vmcnt (T2+T3+T4+T5), B^T ====
// BM=256, BK=64, 512 threads = 8 waves (2M x 4N), wave tile 128 x BN/4.
// Double-buffered LDS. Stage stream order per tile: [B0..B(NBC-1), A0, A2, A1, A3]
//   q0/q1 read B*,A0,A2 (first S-2 loads); q2/q3 read A1,A3 (last 2).
// Waits (per wave, barrier after each for cross-wave visibility):
//   tile boundary: vmcnt(2)  -> next tile's first S-2 loads complete
//   after q1:      vmcnt(S)  -> this tile's A1,A3 complete (S issued at q0)
//   never 0 in the main loop; peeled last tile drains.
// LDS XOR-swizzle byte^=((row&7)<<4) via pre-swizzled global source.
// EPI=1: H = bf16(gelu(acc+b1));  EPI=2: out[scatter] = x + rw*(acc+b2)
template <int BN, int EPI>
__global__ __launch_bounds__(512, 2)
void gemm5(const unsigned short* __restrict__ A, const unsigned short* __restrict__ Bt,
           int M, int N, int K,
           const float* __restrict__ bias,
           unsigned short* __restrict__ Hout,
           const float* __restrict__ x,
           const int* __restrict__ rows,
           const float* __restrict__ rwv,
           float* __restrict__ out) {
  constexpr int NREP = BN / 64;            // B frags per wave per kk
  constexpr int NBC  = BN / 64;            // B stage chunks (64 rows each)
  constexpr int S    = 4 + NBC;            // stage loads per thread per tile
  constexpr int ABYTES = 256 * 128;        // 32 KB
  constexpr int BBYTES = BN * 128;
  constexpr int TB = ABYTES + BBYTES;
  __shared__ __align__(16) char lds[2 * TB];

  const int t = threadIdx.x;
  const int lane = t & 63;
  const int wid = t >> 6;
  const int wm = wid >> 2;                 // 0..1
  const int wn = wid & 3;                  // 0..3

  // XCD-aware bijective swizzle (gridDim.x % 8 == 0 by construction)
  const int nwg = gridDim.x;
  const int qq = nwg >> 3;
  const int nid = (blockIdx.x & 7) * qq + (blockIdx.x >> 3);
  const int gx = N / BN;
  const int by = nid / gx;
  const int bx = nid - by * gx;
  const int bm0 = by * 256;
  const int bn0 = bx * BN;

  const size_t ldb = (size_t)K * 2;        // row bytes for A and Bt
  const char* Ab = (const char*)A;
  const char* Bb = (const char*)Bt;

  // staging: thread t covers LDS bytes [t*16, t*16+16) of each 64-row chunk;
  // chunk row = t>>3, dest slot = t&7, source slot = (t&7)^(row&7)
  const int srow = t >> 3;
  const size_t stage_off = (size_t)srow * ldb + (size_t)((((t & 7) ^ (srow & 7)) * 16));

  // ds_read fragment offsets (swizzled)
  const int arow0 = wm * 128 + (lane & 15);
  const int brow0 = wn * (BN / 4) + (lane & 15);
  const int cbs0 = (((lane >> 4) * 16)     ) ^ ((lane & 7) << 4);  // kk=0
  const int cbs1 = (64 + (lane >> 4) * 16) ^ ((lane & 7) << 4);    // kk=1

  f32x4_t acc[8][NREP];
  f32x4_t zero = {0.f, 0.f, 0.f, 0.f};
#pragma unroll
  for (int i = 0; i < 8; ++i)
#pragma unroll
    for (int j = 0; j < NREP; ++j) acc[i][j] = zero;

  const int NT = K / 64;

  // stage stream order: B0..B(NBC-1), A0, A2, A1, A3
  auto stage = [&](int b, int kt) {
    char* base = lds + b * TB;
    const char* bbase = Bb + (size_t)bn0 * ldb + (size_t)kt * 128 + stage_off;
#pragma unroll
    for (int c = 0; c < NBC; ++c)
      GLD16(bbase + (size_t)(c * 64) * ldb, base + ABYTES + t * 16 + c * 8192);
    const char* abase = Ab + (size_t)bm0 * ldb + (size_t)kt * 128 + stage_off;
    const int order[4] = {0, 2, 1, 3};
#pragma unroll
    for (int i = 0; i < 4; ++i) {
      int cc = order[i];
      GLD16(abase + (size_t)(cc * 64) * ldb, base + t * 16 + cc * 8192);
    }
  };

  // prologue: stage tile 0; first S-2 loads (B*, A0, A2) must land
  stage(0, 0);
  asm volatile("s_waitcnt vmcnt(2)" ::: "memory");
  __builtin_amdgcn_s_barrier();
  __builtin_amdgcn_sched_barrier(0);

  for (int kt = 0; kt < NT; ++kt) {
    const int b = kt & 1;
    const char* Al = lds + b * TB;
    const char* Bl = Al + ABYTES;
    const bool sn = (kt + 1 < NT);
    bf16x8_t bq[NREP][2];
    bf16x8_t am[2][2];

    auto rdA = [&](int q) {
#pragma unroll
      for (int mi = 0; mi < 2; ++mi) {
        const char* ap = Al + (arow0 + (2 * q + mi) * 16) * 128;
        am[mi][0] = *(const bf16x8_t*)(ap + cbs0);
        am[mi][1] = *(const bf16x8_t*)(ap + cbs1);
      }
    };
    auto domfma = [&](int q) {
      __builtin_amdgcn_s_setprio(1);
#pragma unroll
      for (int mi = 0; mi < 2; ++mi)
#pragma unroll
        for (int n = 0; n < NREP; ++n) {
          acc[2 * q + mi][n] = __builtin_amdgcn_mfma_f32_16x16x32_bf16(
              am[mi][0], bq[n][0], acc[2 * q + mi][n], 0, 0, 0);
          acc[2 * q + mi][n] = __builtin_amdgcn_mfma_f32_16x16x32_bf16(
              am[mi][1], bq[n][1], acc[2 * q + mi][n], 0, 0, 0);
        }
      __builtin_amdgcn_s_setprio(0);
    };

    // ---- phase 0: B frags + A(q0) + stage issue ----
#pragma unroll
    for (int n = 0; n < NREP; ++n) {
      const char* bp = Bl + (brow0 + n * 16) * 128;
      bq[n][0] = *(const bf16x8_t*)(bp + cbs0);
      bq[n][1] = *(const bf16x8_t*)(bp + cbs1);
    }
    rdA(0);
    if (sn) stage(b ^ 1, kt + 1);
    __builtin_amdgcn_s_barrier();
    domfma(0);
    __builtin_amdgcn_s_barrier();
    // ---- phase 1 ----
    rdA(1);
    __builtin_amdgcn_s_barrier();
    domfma(1);
    if (sn) {
      if constexpr (S == 8) asm volatile("s_waitcnt vmcnt(8)" ::: "memory");
      else                  asm volatile("s_waitcnt vmcnt(6)" ::: "memory");
    } else {
      asm volatile("s_waitcnt vmcnt(0)" ::: "memory");
    }
    __builtin_amdgcn_s_barrier();
    __builtin_amdgcn_sched_barrier(0);
    // ---- phase 2 ----
    rdA(2);
    __builtin_amdgcn_s_barrier();
    domfma(2);
    __builtin_amdgcn_s_barrier();
    // ---- phase 3 ----
    rdA(3);
    __builtin_amdgcn_s_barrier();
    domfma(3);
    if (sn) asm volatile("s_waitcnt vmcnt(2)" ::: "memory");
    __builtin_amdgcn_s_barrier();
    __builtin_amdgcn_sched_barrier(0);
  }

  // epilogue  (C/D: row = (lane>>4)*4 + qi (M), col = lane&15 (N))
  const int rb = (lane >> 4) * 4;
  const int cc = lane & 15;
  float bs[NREP];
#pragma unroll
  for (int n = 0; n < NREP; ++n)
    bs[n] = bias[bn0 + wn * (BN / 4) + n * 16 + cc];
#pragma unroll
  for (int m = 0; m < 8; ++m) {
#pragma unroll
    for (int qi = 0; qi < 4; ++qi) {
      int grow = bm0 + wm * 128 + m * 16 + rb + qi;
      if (EPI == 1) {
#pragma unroll
        for (int n = 0; n < NREP; ++n) {
          int gcol = bn0 + wn * (BN / 4) + n * 16 + cc;
          float v = acc[m][n][qi] + bs[n];
          float cp = 0.7978845608028654f * (v + 0.044715f * v * v * v);
          float g = v / (1.f + __expf(-2.f * cp));   // tanh-approx gelu
          Hout[(size_t)grow * N + gcol] = f2bf(g);
        }
      } else {
        int batch = grow >> 11;
        int tok = rows[grow];
        float rw = rwv[grow];
        size_t obase = ((size_t)(batch * SEQ + tok)) * DIM;
#pragma unroll
        for (int n = 0; n < NREP; ++n) {
          int gcol = bn0 + wn * (BN / 4) + n * 16 + cc;
          float v = acc[m][n][qi] + bs[n];
          out[obase + gcol] = x[obase + gcol] + rw * v;
        }
      }
    }
  }
}

// ---- aux BCE loss reduction ----
__global__ void aux_kernel(const float* __restrict__ logits, const int* __restrict__ sel,
                           float* __restrict__ out, int out_size) {
  __shared__ float red[16];
  int t = threadIdx.x;
  float sum = 0.f;
  for (int i = t; i < NTOK; i += 1024) {
    float l = logits[i];
    float tgt = sel[i] ? 1.f : 0.f;
    sum += fmaxf(l, 0.f) - l * tgt + log1pf(expf(-fabsf(l)));
  }
#pragma unroll
  for (int off = 32; off > 0; off >>= 1) sum += __shfl_down(sum, off);
  if ((t & 63) == 0) red[t >> 6] = sum;
  __syncthreads();
  if (t == 0) {
    float v = 0.f;
    for (int i = 0; i < 16; ++i) v += red[i];
    out[out_size - 1] = v / (float)NTOK;
  }
}

extern "C" void kernel_launch(void* const* d_in, const int* in_sizes, int n_in,
                              void* d_out, int out_size, void* d_ws, size_t ws_size,
                              hipStream_t stream) {
  const float* x  = (const float*)d_in[0];
  // d_in[1] = attention_mask (unused by reference)
  const float* Wr = (const float*)d_in[2];
  const float* br = (const float*)d_in[3];
  const float* W1 = (const float*)d_in[4];
  const float* b1 = (const float*)d_in[5];
  const float* W2 = (const float*)d_in[6];
  const float* b2 = (const float*)d_in[7];
  float* out = (float*)d_out;

  char* ws = (char*)d_ws;
  float* logits = (float*)(ws);
  float* scores = (float*)(ws + 65536);
  int*   sel    = (int*)(ws + 131072);
  int*   rows   = (int*)(ws + 196608);
  float* rwv    = (float*)(ws + 229376);
  int*   slot   = (int*)(ws + 262144);
  unsigned short* W1t = (unsigned short*)(ws + 327680);
  unsigned short* W2t = (unsigned short*)(ws + 327680 + 8388608);
  unsigned short* Xc  = (unsigned short*)(ws + 327680 + 2 * 8388608);
  unsigned short* H   = (unsigned short*)(ws + 327680 + 2 * 8388608 + 16777216);

  transpose_cast<<<dim3(DFF / 32, DIM / 32), dim3(32, 8), 0, stream>>>(W1, W1t, DIM, DFF);
  transpose_cast<<<dim3(DIM / 32, DFF / 32), dim3(32, 8), 0, stream>>>(W2, W2t, DFF, DIM);
  router_kernel<<<NTOK / 4, 256, 0, stream>>>(x, Wr, br, logits, scores);
  rank_kernel<<<NTOK / 16, 256, 0, stream>>>(scores, sel);
  pack_kernel<<<NB, 1024, 0, stream>>>(scores, sel, rows, rwv, slot);
  gather_copy_kernel<<<NTOK, 256, 0, stream>>>(x, sel, slot, Xc, out);
  gemm5<256, 1><<<(MR / 256) * (DFF / 256), 512, 0, stream>>>(
      Xc, W1t, MR, DFF, DIM, b1, H, nullptr, nullptr, nullptr, nullptr);
  gemm5<128, 2><<<(MR / 256) * (DIM / 128), 512, 0, stream>>>(
      H, W2t, MR, DIM, DFF, b2, nullptr, x, rows, rwv, out);
  aux_kernel<<<1, 1024, 0, stream>>>(logits, sel, out, out_size);
}